// Round 1
// baseline (60.241 us; speedup 1.0000x reference)
//
#include <hip/hip_runtime.h>
#include <math.h>

#define NPTS   18
#define NDIMS  4
#define NITER  15   // num_splines - 1
#define RSTRIDE 28  // floats per table row: 24 used + 4 pad (112 B, 16B-aligned, good bank spread)

__device__ __forceinline__ float sigm(float v) { return 1.0f / (1.0f + expf(-v)); }

// ---------------- Kernel A: tiny MLP, one block per control point ----------------
__global__ __launch_bounds__(256) void mlp_kernel(
    const float* __restrict__ W1, const float* __restrict__ b1,
    const float* __restrict__ W2, const float* __restrict__ b2,
    const float* __restrict__ W3, const float* __restrict__ b3,
    const float* __restrict__ W4, const float* __restrict__ b4,
    const float* __restrict__ W5, const float* __restrict__ b5,
    const float* __restrict__ W6, const float* __restrict__ b6,
    float* __restrict__ P)
{
    __shared__ float bufA[256];
    __shared__ float bufB[256];
    const int t = threadIdx.x;
    const float pos = (float)(blockIdx.x + 1);

    // L1: (1 -> 16), sigmoid
    if (t < 16) bufA[t] = sigm(fmaf(W1[t], pos, b1[t]));
    __syncthreads();

    // L2: (16 -> 64), sigmoid
    if (t < 64) {
        float a = b2[t];
        #pragma unroll
        for (int i = 0; i < 16; ++i) a = fmaf(W2[t*16 + i], bufA[i], a);
        bufB[t] = sigm(a);
    }
    __syncthreads();

    // L3: (64 -> 256), relu
    {
        float a = b3[t];
        #pragma unroll 8
        for (int i = 0; i < 64; ++i) a = fmaf(W3[t*64 + i], bufB[i], a);
        bufA[t] = fmaxf(a, 0.0f);
    }
    __syncthreads();

    // L4: (256 -> 64), relu
    if (t < 64) {
        float a0 = 0.f, a1 = 0.f, a2 = 0.f, a3 = 0.f;
        const float* w = W4 + t*256;
        #pragma unroll 4
        for (int i = 0; i < 256; i += 4) {
            a0 = fmaf(w[i+0], bufA[i+0], a0);
            a1 = fmaf(w[i+1], bufA[i+1], a1);
            a2 = fmaf(w[i+2], bufA[i+2], a2);
            a3 = fmaf(w[i+3], bufA[i+3], a3);
        }
        bufB[t] = fmaxf(b4[t] + ((a0 + a1) + (a2 + a3)), 0.0f);
    }
    __syncthreads();

    // L5: (64 -> 16), relu
    if (t < 16) {
        float a = b5[t];
        #pragma unroll
        for (int i = 0; i < 64; ++i) a = fmaf(W5[t*64 + i], bufB[i], a);
        bufA[t] = fmaxf(a, 0.0f);
    }
    __syncthreads();

    // L6: (16 -> 4), then cumsum over dims
    if (t < 4) {
        float a = b6[t];
        #pragma unroll
        for (int i = 0; i < 16; ++i) a = fmaf(W6[t*16 + i], bufA[i], a);
        bufB[t] = a;
    }
    __syncthreads();

    if (t == 0) {
        float c = 0.0f;
        for (int j = 0; j < NDIMS; ++j) {
            c += bufB[j];
            P[blockIdx.x * NDIMS + j] = c;
        }
    }
}

// ---------------- Kernel A2: 15-step control-point recurrence -> table ----------------
// Table row i (stride RSTRIDE floats): [Pt0(4) Pt1(4) Pt2(4) Pn0(4) Pn1(4) Pn2(4) pad(4)]
__global__ void build_table(const float* __restrict__ P, float* __restrict__ tbl)
{
    const int j = threadIdx.x;  // dim 0..3
    if (j >= NDIMS) return;
    float P0 = P[0*NDIMS + j];
    float P1 = P[1*NDIMS + j];
    float P2 = P[2*NDIMS + j];
    for (int i = 0; i < NITER; ++i) {
        float Pnext = P[(3 + i)*NDIMS + j];
        float p0 = (P0 + P2) * 0.25f + P1 * 0.5f;
        float p2 = Pnext;
        float p1 = 2.0f * (P2 - (p0 + p2) * 0.25f);
        float* row = tbl + i * RSTRIDE;
        row[0*4 + j] = P0; row[1*4 + j] = P1; row[2*4 + j] = P2;
        row[3*4 + j] = p0; row[4*4 + j] = p1; row[5*4 + j] = p2;
        P0 = p0; P1 = p1; P2 = p2;
    }
}

// ---------------- Kernel B: per-element spline evaluation ----------------
__device__ __forceinline__ float4 eval_spline(float xc, const float* __restrict__ s)
{
    float u  = xc * 15.0f;               // x * (num_splines - 1)
    float fi = floorf(u);
    fi = fminf(fmaxf(fi, 0.0f), 14.0f);  // last matching choice == floor bucket
    float d  = (u - fi) * 0.5f;          // in [0, 0.5)

    const float* row = s + (int)fi * RSTRIDE;
    float4 Pt0 = *(const float4*)(row + 0);
    float4 Pt1 = *(const float4*)(row + 4);
    float4 Pt2 = *(const float4*)(row + 8);
    float4 Pn0 = *(const float4*)(row + 12);
    float4 Pn1 = *(const float4*)(row + 16);
    float4 Pn2 = *(const float4*)(row + 20);

    // Bezier basis: prev at (d+0.5), curr at d
    float dp  = d + 0.5f, omp = 1.0f - dp;
    float cp0 = omp*omp, cp1 = 2.0f*dp*omp, cp2 = dp*dp;
    float omd = 1.0f - d;
    float cc0 = omd*omd, cc1 = 2.0f*d*omd, cc2 = d*d;

    float cp = cospif(d);
    float sp = sinpif(d);
    float wc = cp*cp, ws = sp*sp;

    float4 r;
    r.x = wc*fmaf(cp0, Pt0.x, fmaf(cp1, Pt1.x, cp2*Pt2.x)) + ws*fmaf(cc0, Pn0.x, fmaf(cc1, Pn1.x, cc2*Pn2.x));
    r.y = wc*fmaf(cp0, Pt0.y, fmaf(cp1, Pt1.y, cp2*Pt2.y)) + ws*fmaf(cc0, Pn0.y, fmaf(cc1, Pn1.y, cc2*Pn2.y));
    r.z = wc*fmaf(cp0, Pt0.z, fmaf(cp1, Pt1.z, cp2*Pt2.z)) + ws*fmaf(cc0, Pn0.z, fmaf(cc1, Pn1.z, cc2*Pn2.z));
    r.w = wc*fmaf(cp0, Pt0.w, fmaf(cp1, Pt1.w, cp2*Pt2.w)) + ws*fmaf(cc0, Pn0.w, fmaf(cc1, Pn1.w, cc2*Pn2.w));
    return r;
}

__global__ __launch_bounds__(256) void spline_kernel(
    const float* __restrict__ x, const float* __restrict__ tbl,
    float* __restrict__ out, int n)
{
    __shared__ float s[NITER * RSTRIDE];
    for (int k = threadIdx.x; k < NITER * RSTRIDE; k += 256) s[k] = tbl[k];
    __syncthreads();

    const int idx  = blockIdx.x * 256 + threadIdx.x;
    const int base = idx * 4;
    float4* out4 = (float4*)out;

    if (base + 3 < n) {
        float4 xv = ((const float4*)x)[idx];
        out4[base + 0] = eval_spline(xv.x, s);
        out4[base + 1] = eval_spline(xv.y, s);
        out4[base + 2] = eval_spline(xv.z, s);
        out4[base + 3] = eval_spline(xv.w, s);
    } else if (base < n) {
        for (int c = 0; c < n - base; ++c)
            out4[base + c] = eval_spline(x[base + c], s);
    }
}

// ---------------- launch ----------------
extern "C" void kernel_launch(void* const* d_in, const int* in_sizes, int n_in,
                              void* d_out, int out_size, void* d_ws, size_t ws_size,
                              hipStream_t stream)
{
    const float* x  = (const float*)d_in[0];
    const float* W1 = (const float*)d_in[1];  const float* b1 = (const float*)d_in[2];
    const float* W2 = (const float*)d_in[3];  const float* b2 = (const float*)d_in[4];
    const float* W3 = (const float*)d_in[5];  const float* b3 = (const float*)d_in[6];
    const float* W4 = (const float*)d_in[7];  const float* b4 = (const float*)d_in[8];
    const float* W5 = (const float*)d_in[9];  const float* b5 = (const float*)d_in[10];
    const float* W6 = (const float*)d_in[11]; const float* b6 = (const float*)d_in[12];

    float* P   = (float*)d_ws;        // 72 floats
    float* tbl = (float*)d_ws + 128;  // 15 * 28 floats, 16B-aligned offset

    const int n = in_sizes[0];

    mlp_kernel<<<NPTS, 256, 0, stream>>>(W1, b1, W2, b2, W3, b3, W4, b4, W5, b5, W6, b6, P);
    build_table<<<1, 64, 0, stream>>>(P, tbl);

    const int n4 = (n + 3) / 4;
    const int blocks = (n4 + 255) / 256;
    spline_kernel<<<blocks, 256, 0, stream>>>(x, tbl, (float*)d_out, n);
}